// Round 16
// baseline (42.291 us; speedup 1.0000x reference)
//
#include <hip/hip_runtime.h>

constexpr int DSZ = 192, HSZ = 192, WSZ = 192, BSZ = 2;
constexpr int WQ  = WSZ / 4;          // 48 float4 per row
constexpr int RB  = 4;                // own rows per thread
constexpr int CH  = 6;                // planes marched per thread
constexpr int TPB = 192;              // 48 wq x 4 bands -> 16 rows per block
constexpr int HB  = RB * (TPB / WQ);  // 16 rows per block
constexpr int NHB = HSZ / HB;         // 12
constexpr int NDC = DSZ / CH;         // 32
constexpr int NBLOCKS = BSZ * NDC * NHB;  // 768 = 3 blocks/CU, %8==0
constexpr int HW = HSZ * WSZ;
constexpr float SMOOTH = 1e-5f;

__device__ __forceinline__ float4 ld4(const float* __restrict__ p) {
    return *reinterpret_cast<const float4*>(p);
}

__device__ __forceinline__ float fsqrt(float x) {
    return __builtin_amdgcn_sqrtf(x);
}

__device__ __forceinline__ void mag4(float4 c, float4 hm, float4 hn,
                                     float4 d0, float4 d1, float wl, float wr,
                                     float o[4]) {
    float gx0 = d1.x - d0.x, gx1 = d1.y - d0.y, gx2 = d1.z - d0.z, gx3 = d1.w - d0.w;
    float gy0 = hn.x - hm.x, gy1 = hn.y - hm.y, gy2 = hn.z - hm.z, gy3 = hn.w - hm.w;
    float gz0 = c.y - wl,    gz1 = c.z - c.x,   gz2 = c.w - c.y,   gz3 = wr - c.z;
    o[0] = fsqrt(fmaf(gx0, gx0, fmaf(gy0, gy0, fmaf(gz0, gz0, SMOOTH))));
    o[1] = fsqrt(fmaf(gx1, gx1, fmaf(gy1, gy1, fmaf(gz1, gz1, SMOOTH))));
    o[2] = fsqrt(fmaf(gx2, gx2, fmaf(gy2, gy2, fmaf(gz2, gz2, SMOOTH))));
    o[3] = fsqrt(fmaf(gx3, gx3, fmaf(gy3, gy3, fmaf(gz3, gz3, SMOOTH))));
}

// w-edges via cross-lane shuffle. Lane boundaries that cross rows coincide
// exactly with the wq==0 / wq==WQ-1 masks, so cross-row garbage is masked.
__device__ __forceinline__ void edges(float4 r, int wq, float& wl, float& wr) {
    float up = __shfl_up(r.w, 1);
    float dn = __shfl_down(r.x, 1);
    wl = (wq > 0)      ? up : 0.f;
    wr = (wq < WQ - 1) ? dn : 0.f;
}

__global__ __launch_bounds__(TPB)
void bl_main(const float* __restrict__ pred,
             const float* __restrict__ target,
             double* __restrict__ acc) {
    const int bid = (int)blockIdx.x;
    const int swz = (bid & 7) * (NBLOCKS / 8) + (bid >> 3);  // XCD-chunked
    const int hb  = swz % NHB;
    int t         = swz / NHB;
    const int dc  = t % NDC;
    const int b   = t / NDC;
    const int dstart = dc * CH;

    const int tid  = threadIdx.x;
    const int wq   = tid % WQ;
    const int band = tid / WQ;                 // 0..3
    const int gh   = hb * HB + band * RB;      // first own row

    const bool okm = (gh > 0);                 // halo row gh-1 exists
    const bool okp = (gh + RB < HSZ);          // halo row gh+RB exists

    const float4 z = make_float4(0.f, 0.f, 0.f, 0.f);
    // P0/T0 point at row gh-1 (guarded by okm; never dereferenced when invalid)
    const float* __restrict__ P0 =
        pred   + (size_t)b * DSZ * HW + (size_t)(gh - 1) * WSZ + wq * 4;
    const float* __restrict__ T0 =
        target + (size_t)b * DSZ * HW + (size_t)(gh - 1) * WSZ + wq * 4;

    // windows: Z = centers at plane d-1 (4 rows), A = 6 rows at plane d,
    // B = 6 rows at plane d+1 (loaded each step). All static-indexed.
    float4 pZ[RB], pA[RB + 2], pB[RB + 2];
    float4 tZ[RB], tA[RB + 2], tB[RB + 2];

    // ---- warmup: Z at dstart-1 (centers only), A at dstart
    {
        const bool vd = (dstart > 0);
        const size_t zo = (size_t)(dstart - 1) * HW;
        #pragma unroll
        for (int r = 0; r < RB; ++r) {
            const size_t ro = (size_t)(r + 1) * WSZ + zo;
            pZ[r] = vd ? ld4(P0 + ro) : z;
            tZ[r] = vd ? ld4(T0 + ro) : z;
        }
        const size_t ao = (size_t)dstart * HW;
        pA[0] = okm ? ld4(P0 + ao) : z;
        tA[0] = okm ? ld4(T0 + ao) : z;
        #pragma unroll
        for (int i = 1; i <= RB; ++i) {
            const size_t ro = (size_t)i * WSZ + ao;
            pA[i] = ld4(P0 + ro);
            tA[i] = ld4(T0 + ro);
        }
        pA[RB + 1] = okp ? ld4(P0 + (size_t)(RB + 1) * WSZ + ao) : z;
        tA[RB + 1] = okp ? ld4(T0 + (size_t)(RB + 1) * WSZ + ao) : z;
    }

    float s_pt = 0.f, s_p = 0.f, s_t = 0.f;

    #pragma unroll 1
    for (int s = 0; s < CH; ++s) {
        const int d  = dstart + s;
        const bool vq = (d + 1 < DSZ);
        const size_t qo = (size_t)(d + 1) * HW;

        // load 6 rows of plane d+1 (interleaved pred/target for early waitcnt)
        pB[0] = (vq && okm) ? ld4(P0 + qo) : z;
        tB[0] = (vq && okm) ? ld4(T0 + qo) : z;
        #pragma unroll
        for (int i = 1; i <= RB; ++i) {
            const size_t ro = (size_t)i * WSZ + qo;
            pB[i] = vq ? ld4(P0 + ro) : z;
            tB[i] = vq ? ld4(T0 + ro) : z;
        }
        pB[RB + 1] = (vq && okp) ? ld4(P0 + (size_t)(RB + 1) * WSZ + qo) : z;
        tB[RB + 1] = (vq && okp) ? ld4(T0 + (size_t)(RB + 1) * WSZ + qo) : z;

        // compute plane d for own rows r=0..3
        #pragma unroll
        for (int r = 0; r < RB; ++r) {
            float mp[4], mt[4];
            {
                float wl, wr;
                edges(pA[r + 1], wq, wl, wr);
                mag4(pA[r + 1], pA[r], pA[r + 2], pZ[r], pB[r + 1], wl, wr, mp);
            }
            {
                float wl, wr;
                edges(tA[r + 1], wq, wl, wr);
                mag4(tA[r + 1], tA[r], tA[r + 2], tZ[r], tB[r + 1], wl, wr, mt);
            }
            #pragma unroll
            for (int j = 0; j < 4; ++j) {
                s_pt = fmaf(mp[j], mt[j], s_pt);
                s_p += mp[j];
                s_t += mt[j];
            }
        }

        // roll windows (all static)
        #pragma unroll
        for (int r = 0; r < RB; ++r) {
            pZ[r] = pA[r + 1];
            tZ[r] = tA[r + 1];
        }
        #pragma unroll
        for (int i = 0; i < RB + 2; ++i) {
            pA[i] = pB[i];
            tA[i] = tB[i];
        }
    }

    // ---- reduction (3 waves)
    #pragma unroll
    for (int off = 32; off; off >>= 1) {
        s_pt += __shfl_down(s_pt, off);
        s_p  += __shfl_down(s_p,  off);
        s_t  += __shfl_down(s_t,  off);
    }

    __shared__ float red[3][4];
    const int lane = tid & 63;
    const int wid  = tid >> 6;
    if (lane == 0) {
        red[wid][0] = s_pt;
        red[wid][1] = s_p;
        red[wid][2] = s_t;
    }
    __syncthreads();
    if (tid == 0) {
        double a_pt = 0.0, a_p = 0.0, a_t = 0.0;
        #pragma unroll
        for (int k = 0; k < 3; ++k) {
            a_pt += (double)red[k][0];
            a_p  += (double)red[k][1];
            a_t  += (double)red[k][2];
        }
        atomicAdd(&acc[0],  a_pt);
        atomicAdd(&acc[8],  a_p);
        atomicAdd(&acc[16], a_t);
    }
}

__global__ void bl_final(const double* __restrict__ acc, float* __restrict__ out) {
    const double I = acc[0];
    const double Pm = acc[8];
    const double Tm = acc[16];
    const double dice = (2.0 * I + 1e-5) / (Pm + Tm + 1e-5);
    out[0] = (float)(1.0 - dice);
}

extern "C" void kernel_launch(void* const* d_in, const int* in_sizes, int n_in,
                              void* d_out, int out_size, void* d_ws, size_t ws_size,
                              hipStream_t stream) {
    const float* pred   = (const float*)d_in[0];
    const float* target = (const float*)d_in[1];
    double* acc = (double*)d_ws;

    (void)hipMemsetAsync(d_ws, 0, 17 * sizeof(double), stream);
    bl_main<<<NBLOCKS, TPB, 0, stream>>>(pred, target, acc);
    bl_final<<<1, 1, 0, stream>>>(acc, (float*)d_out);
}